// Round 6
// baseline (245.468 us; speedup 1.0000x reference)
//
#include <hip/hip_runtime.h>
#include <hip/hip_bf16.h>

// B=2, T=2048, C=768, H=12, D=64. 3C=2304. BT=4096.
// R6 = SPLIT-MEASUREMENT ROUND: kernels byte-identical to R4/R5. Launch
// counts: prologue x2, gemm_qkv x2, attn x3, gemm_proj x2 (all idempotent).
// With R4 (each x1, 144.4) and R5 (each x2, 217.6 -> Sum+4g = 73.2):
//   dur - 144.4 - 73.2 = attn_time + 1 launch gap   (model-free isolation)

using half4   = __attribute__((ext_vector_type(4))) _Float16;
using half8   = __attribute__((ext_vector_type(8))) _Float16;
using floatx4 = __attribute__((ext_vector_type(4))) float;

#define T_SEQ 2048
#define NHEAD 12
#define HDIM 64
#define C3 2304
#define CDIM 768
#define BT 4096
#define BH 24

static __device__ inline _Float16 f2h(float f) { return (_Float16)f; }

// lgkm-only workgroup barrier: waits DS/SMEM ops (lgkmcnt(0)), leaves
// vmcnt (global loads) in flight. 0xc07f = vmcnt(63) expcnt(7) lgkmcnt(0).
static __device__ inline void bar_lgkm() {
    __builtin_amdgcn_s_waitcnt(0xc07f);
    __builtin_amdgcn_s_barrier();
}

// ---------------- prologue: weight transposes only --------------------------
// blocks [0,1728): wTa; [1728,2304): wTp
__global__ __launch_bounds__(256)
void prologue(const float* __restrict__ wa, const float* __restrict__ wp,
              _Float16* __restrict__ wTa, _Float16* __restrict__ wTp) {
    __shared__ float tile[32][33];
    int blk = blockIdx.x, tid = threadIdx.x;
    const float* w; _Float16* wT; int K, N, bx, by;
    if (blk < 1728) { w = wa; wT = wTa; K = CDIM; N = C3; bx = blk % 72; by = blk / 72; }
    else { int b2 = blk - 1728; w = wp; wT = wTp; K = CDIM; N = CDIM; bx = b2 % 24; by = b2 / 24; }
    int tx = tid & 31, ty = tid >> 5;
    #pragma unroll
    for (int j = 0; j < 32; j += 8) {
        int k = by * 32 + ty + j, n = bx * 32 + tx;
        tile[ty + j][tx] = w[(long)k * N + n];
    }
    __syncthreads();
    #pragma unroll
    for (int j = 0; j < 32; j += 8) {
        int nO = bx * 32 + ty + j, kO = by * 32 + tx;
        wT[(long)nO * K + kO] = f2h(tile[tx][ty + j]);
    }
}

// ---------------- QKV GEMM: 128x96 tile, BK=64, reg-prefetch, fused x cast ---
// Grid 32x24 = 768 blocks = 3/CU exact. A read directly from fp32 x.
__global__ __launch_bounds__(256)
void gemm_qkv(const float* __restrict__ X, const _Float16* __restrict__ Bt,
              const float* __restrict__ bias,
              _Float16* __restrict__ Qb, _Float16* __restrict__ Kb,
              _Float16* __restrict__ Vt) {
    __shared__ __align__(16) _Float16 As[128 * 72];
    __shared__ __align__(16) _Float16 Bs[96 * 72];
    const int K = CDIM;
    int tid = threadIdx.x;
    int m0 = blockIdx.x * 128, n0 = blockIdx.y * 96;
    int w = tid >> 6, l = tid & 63;
    int wm = (w >> 1) * 64, wn = (w & 1) * 48;
    int lr = l & 15, lq = l >> 4;

    int rs = tid >> 3, cs = (tid & 7) * 8;   // row step 32 per j

    floatx4 acc[4][3] = {};

    floatx4 Arf[4][2]; half8 Br[3];
    #pragma unroll
    for (int j = 0; j < 4; ++j) {
        Arf[j][0] = *(const floatx4*)&X[(long)(m0 + j * 32 + rs) * K + cs];
        Arf[j][1] = *(const floatx4*)&X[(long)(m0 + j * 32 + rs) * K + cs + 4];
    }
    #pragma unroll
    for (int j = 0; j < 3; ++j)
        Br[j] = *(const half8*)&Bt[(long)(n0 + j * 32 + rs) * K + cs];

    for (int kb = 0; kb < K; kb += 64) {
        #pragma unroll
        for (int j = 0; j < 4; ++j) {
            half8 h;
            #pragma unroll
            for (int e = 0; e < 4; ++e) { h[e] = f2h(Arf[j][0][e]); h[4 + e] = f2h(Arf[j][1][e]); }
            *(half8*)&As[(j * 32 + rs) * 72 + cs] = h;
        }
        #pragma unroll
        for (int j = 0; j < 3; ++j)
            *(half8*)&Bs[(j * 32 + rs) * 72 + cs] = Br[j];
        bar_lgkm();                      // writes visible; vmcnt stays in flight
        if (kb + 64 < K) {
            #pragma unroll
            for (int j = 0; j < 4; ++j) {
                Arf[j][0] = *(const floatx4*)&X[(long)(m0 + j * 32 + rs) * K + kb + 64 + cs];
                Arf[j][1] = *(const floatx4*)&X[(long)(m0 + j * 32 + rs) * K + kb + 64 + cs + 4];
            }
            #pragma unroll
            for (int j = 0; j < 3; ++j)
                Br[j] = *(const half8*)&Bt[(long)(n0 + j * 32 + rs) * K + kb + 64 + cs];
        }
        #pragma unroll
        for (int kh = 0; kh < 2; ++kh) {
            half8 af[4], bf[3];
            #pragma unroll
            for (int i = 0; i < 4; ++i)
                af[i] = *(const half8*)&As[(wm + i * 16 + lr) * 72 + kh * 32 + lq * 8];
            #pragma unroll
            for (int i = 0; i < 3; ++i)
                bf[i] = *(const half8*)&Bs[(wn + i * 16 + lr) * 72 + kh * 32 + lq * 8];
            #pragma unroll
            for (int mi = 0; mi < 4; ++mi)
                #pragma unroll
                for (int ni = 0; ni < 3; ++ni)
                    acc[mi][ni] = __builtin_amdgcn_mfma_f32_16x16x32_f16(af[mi], bf[ni], acc[mi][ni], 0, 0, 0);
        }
        bar_lgkm();                      // reads retired; prefetch still in flight
    }

    int region = n0 / CDIM;
    if (region < 2) {
        _Float16* O = region ? Kb : Qb;
        int nc0 = n0 - region * CDIM + wn;
        #pragma unroll
        for (int mi = 0; mi < 4; ++mi)
            #pragma unroll
            for (int ni = 0; ni < 3; ++ni) {
                int col = nc0 + ni * 16 + lr;
                float bsc = bias[region * CDIM + col];
                #pragma unroll
                for (int r = 0; r < 4; ++r) {
                    int row = m0 + wm + mi * 16 + lq * 4 + r;
                    O[(long)row * CDIM + col] = f2h(acc[mi][ni][r] + bsc);
                }
            }
    } else {
        #pragma unroll
        for (int mi = 0; mi < 4; ++mi)
            #pragma unroll
            for (int ni = 0; ni < 3; ++ni) {
                int cv = n0 - 2 * CDIM + wn + ni * 16 + lr;    // 0..767
                float bsc = bias[2 * CDIM + cv];
                int h = cv >> 6, d = cv & 63;
                int t0 = m0 + wm + mi * 16 + lq * 4;
                int bb = t0 >> 11, t = t0 & 2047;
                half4 hv;
                #pragma unroll
                for (int r = 0; r < 4; ++r) hv[r] = f2h(acc[mi][ni][r] + bsc);
                *(half4*)&Vt[(((long)bb * NHEAD + h) * HDIM + d) * T_SEQ + t] = hv;
            }
    }
}

// ---------------- proj GEMM: 64x96 tile, BK=64, reg-prefetch, fp32 out -------
// Grid 64x8 = 512 blocks = 2/CU exact.
__global__ __launch_bounds__(256)
void gemm_proj(const _Float16* __restrict__ A, const _Float16* __restrict__ Bt,
               const float* __restrict__ bias, float* __restrict__ Cout) {
    __shared__ __align__(16) _Float16 As[64 * 72];
    __shared__ __align__(16) _Float16 Bs[96 * 72];
    const int K = CDIM, N = CDIM;
    int tid = threadIdx.x;
    int m0 = blockIdx.x * 64, n0 = blockIdx.y * 96;
    int w = tid >> 6, l = tid & 63;
    int wm = (w >> 1) * 32, wn = (w & 1) * 48;
    int lr = l & 15, lq = l >> 4;

    int rs = tid >> 3, cs = (tid & 7) * 8;

    floatx4 acc[2][3] = {};

    half8 Ar[2], Br[3];
    #pragma unroll
    for (int j = 0; j < 2; ++j)
        Ar[j] = *(const half8*)&A[(long)(m0 + j * 32 + rs) * K + cs];
    #pragma unroll
    for (int j = 0; j < 3; ++j)
        Br[j] = *(const half8*)&Bt[(long)(n0 + j * 32 + rs) * K + cs];

    for (int kb = 0; kb < K; kb += 64) {
        #pragma unroll
        for (int j = 0; j < 2; ++j)
            *(half8*)&As[(j * 32 + rs) * 72 + cs] = Ar[j];
        #pragma unroll
        for (int j = 0; j < 3; ++j)
            *(half8*)&Bs[(j * 32 + rs) * 72 + cs] = Br[j];
        bar_lgkm();
        if (kb + 64 < K) {
            #pragma unroll
            for (int j = 0; j < 2; ++j)
                Ar[j] = *(const half8*)&A[(long)(m0 + j * 32 + rs) * K + kb + 64 + cs];
            #pragma unroll
            for (int j = 0; j < 3; ++j)
                Br[j] = *(const half8*)&Bt[(long)(n0 + j * 32 + rs) * K + kb + 64 + cs];
        }
        #pragma unroll
        for (int kh = 0; kh < 2; ++kh) {
            half8 af[2], bf[3];
            #pragma unroll
            for (int i = 0; i < 2; ++i)
                af[i] = *(const half8*)&As[(wm + i * 16 + lr) * 72 + kh * 32 + lq * 8];
            #pragma unroll
            for (int i = 0; i < 3; ++i)
                bf[i] = *(const half8*)&Bs[(wn + i * 16 + lr) * 72 + kh * 32 + lq * 8];
            #pragma unroll
            for (int mi = 0; mi < 2; ++mi)
                #pragma unroll
                for (int ni = 0; ni < 3; ++ni)
                    acc[mi][ni] = __builtin_amdgcn_mfma_f32_16x16x32_f16(af[mi], bf[ni], acc[mi][ni], 0, 0, 0);
        }
        bar_lgkm();
    }
    #pragma unroll
    for (int mi = 0; mi < 2; ++mi)
        #pragma unroll
        for (int ni = 0; ni < 3; ++ni) {
            int col = n0 + wn + ni * 16 + lr;
            float b = bias[col];
            #pragma unroll
            for (int r = 0; r < 4; ++r) {
                int row = m0 + wm + mi * 16 + lq * 4 + r;
                Cout[(long)row * N + col] = acc[mi][ni][r] + b;
            }
        }
}

// ---------------- causal flash attention: S^T, 4 waves = 2q-strip x 2key-half
__global__ __launch_bounds__(256)
void attn_kernel(const _Float16* __restrict__ Qb, const _Float16* __restrict__ Kb,
                 const _Float16* __restrict__ Vt, _Float16* __restrict__ y) {
    __shared__ __align__(16) _Float16 Ks[128 * 72];     // [key][d]   18432 B
    __shared__ __align__(16) _Float16 Vs[64 * 136];     // [d][key]   17408 B
    __shared__ __align__(16) _Float16 Ps[64 * 136];     // [q][key]   17408 B
    int tid = threadIdx.x;
    int w = tid >> 6, l = tid & 63;
    int lr = l & 15, lq = l >> 4;
    int qs = (w & 1) * 32;          // q-strip base within 64-q block
    int kh2 = (w >> 1) * 64;        // key-half base within 128-key tile
    int i = blockIdx.x;
    int round = i >> 8, c = i & 255;
    int r_ = (round == 0) ? c : (round == 1 ? 767 - c : 256 + c);
    int qb = 31 - r_ / 24;
    int bh = r_ % 24;
    int b = bh / NHEAD, h = bh % NHEAD;

    const _Float16* Qp = Qb + (long)b * T_SEQ * CDIM + h * HDIM;
    const _Float16* Kg = Kb + (long)b * T_SEQ * CDIM + h * HDIM;
    const _Float16* Vg = Vt + (long)bh * HDIM * T_SEQ;

    int kr = tid >> 3, kc = (tid & 7) * 8;     // K staging: rows j*32 + kr
    int vr = tid >> 4, vc = (tid & 15) * 8;    // V staging: rows j*16 + vr

    const float qscale = 0.125f * 1.44269504f;
    half8 aq[2][2];                            // [strip][khd]
    #pragma unroll
    for (int st = 0; st < 2; ++st)
        #pragma unroll
        for (int kk = 0; kk < 2; ++kk) {
            aq[st][kk] = *(const half8*)&Qp[(long)(qb * 64 + qs + st * 16 + lr) * CDIM + kk * 32 + lq * 8];
            #pragma unroll
            for (int j = 0; j < 8; ++j) aq[st][kk][j] = f2h((float)aq[st][kk][j] * qscale);
        }

    int nk = (qb + 2) >> 1;   // 128-key tiles covering [0, qb*64+64)

    half8 Kr[4], Vr[4];
    #pragma unroll
    for (int j = 0; j < 4; ++j) {
        Kr[j] = *(const half8*)&Kg[(long)(j * 32 + kr) * CDIM + kc];
        Vr[j] = *(const half8*)&Vg[(long)(j * 16 + vr) * T_SEQ + vc];
    }

    float psum[2] = {0.f, 0.f};                // per strip; lane's q = qs+st*16+lr
    floatx4 acc[4][2] = {};                    // [n][strip]
    int qrow0 = qb * 64 + qs + lr, qrow1 = qb * 64 + qs + 16 + lr;

    for (int kt = 0; kt < nk; ++kt) {
        int kbase = kt * 128;
        #pragma unroll
        for (int j = 0; j < 4; ++j) {
            *(half8*)&Ks[(j * 32 + kr) * 72 + kc] = Kr[j];
            *(half8*)&Vs[(j * 16 + vr) * 136 + vc] = Vr[j];
        }
        bar_lgkm();                  // K/V writes visible; vmcnt free-running
        if (kt + 1 < nk) {
            int nb = kbase + 128;
            #pragma unroll
            for (int j = 0; j < 4; ++j) {
                Kr[j] = *(const half8*)&Kg[(long)(nb + j * 32 + kr) * CDIM + kc];
                Vr[j] = *(const half8*)&Vg[(long)(j * 16 + vr) * T_SEQ + nb + vc];
            }
        }

        // S^T = K Q^T over this wave's 64-key half x 32-q strip.
        floatx4 sacc[4][2];
        #pragma unroll
        for (int s = 0; s < 4; ++s)
            #pragma unroll
            for (int st = 0; st < 2; ++st) sacc[s][st] = floatx4{0.f, 0.f, 0.f, 0.f};
        #pragma unroll
        for (int s = 0; s < 4; ++s) {
            #pragma unroll
            for (int kk = 0; kk < 2; ++kk) {
                half8 bk = *(const half8*)&Ks[(kh2 + s * 16 + lr) * 72 + kk * 32 + lq * 8];
                sacc[s][0] = __builtin_amdgcn_mfma_f32_16x16x32_f16(bk, aq[0][kk], sacc[s][0], 0, 0, 0);
                sacc[s][1] = __builtin_amdgcn_mfma_f32_16x16x32_f16(bk, aq[1][kk], sacc[s][1], 0, 0, 0);
            }
        }

        if (kt == nk - 1) {   // tile containing the diagonal
            #pragma unroll
            for (int s = 0; s < 4; ++s) {
                half4 hv0, hv1;
                #pragma unroll
                for (int r = 0; r < 4; ++r) {
                    int key = kbase + kh2 + s * 16 + lq * 4 + r;
                    float p0 = (key > qrow0) ? 0.f : __builtin_amdgcn_exp2f(sacc[s][0][r]);
                    float p1 = (key > qrow1) ? 0.f : __builtin_amdgcn_exp2f(sacc[s][1][r]);
                    psum[0] += p0; psum[1] += p1;
                    hv0[r] = f2h(p0); hv1[r] = f2h(p1);
                }
                *(half4*)&Ps[(qs + lr) * 136 + kh2 + s * 16 + lq * 4] = hv0;
                *(half4*)&Ps[(qs + 16 + lr) * 136 + kh2 + s * 16 + lq * 4] = hv1;
            }
        } else {
            #pragma unroll
            for (int s = 0; s < 4; ++s) {
                half4 hv0, hv1;
                #pragma unroll
                for (int r = 0; r < 4; ++r) {
                    float p0 = __builtin_amdgcn_exp2f(sacc[s][0][r]);
                    float p1 = __builtin_amdgcn_exp2f(sacc[s][1][r]);
                    psum[0] += p0; psum[1] += p1;
                    hv0[r] = f2h(p0); hv1[r] = f2h(p1);
                }
                *(half4*)&Ps[(qs + lr) * 136 + kh2 + s * 16 + lq * 4] = hv0;
                *(half4*)&Ps[(qs + 16 + lr) * 136 + kh2 + s * 16 + lq * 4] = hv1;
            }
        }

        // PV over this wave's key-half: acc[n][strip] partial (reduced later).
        half8 ap[2][2];
        #pragma unroll
        for (int st = 0; st < 2; ++st)
            #pragma unroll
            for (int kk = 0; kk < 2; ++kk)
                ap[st][kk] = *(const half8*)&Ps[(qs + st * 16 + lr) * 136 + kh2 + kk * 32 + lq * 8];
        #pragma unroll
        for (int n = 0; n < 4; ++n) {
            #pragma unroll
            for (int kk = 0; kk < 2; ++kk) {
                half8 bv = *(const half8*)&Vs[(n * 16 + lr) * 136 + kh2 + kk * 32 + lq * 8];
                acc[n][0] = __builtin_amdgcn_mfma_f32_16x16x32_f16(ap[0][kk], bv, acc[n][0], 0, 0, 0);
                acc[n][1] = __builtin_amdgcn_mfma_f32_16x16x32_f16(ap[1][kk], bv, acc[n][1], 0, 0, 0);
            }
        }
        bar_lgkm();                  // reads retired before next K/V overwrite
    }

    // cross-pair reduction: waves 2,3 hand their partials to waves 0,1 via Ks.
    float* red = (float*)Ks;                   // 18432 B >= 2*64*36*4 = 18432 B
    int slot = ((w & 1) * 64 + l) * 36;
    if (w >= 2) {
        #pragma unroll
        for (int n = 0; n < 4; ++n)
            #pragma unroll
            for (int st = 0; st < 2; ++st)
                *(floatx4*)&red[slot + (n * 2 + st) * 4] = acc[n][st];
        red[slot + 32] = psum[0];
        red[slot + 33] = psum[1];
    }
    __syncthreads();
    if (w < 2) {
        #pragma unroll
        for (int n = 0; n < 4; ++n)
            #pragma unroll
            for (int st = 0; st < 2; ++st) {
                floatx4 t = *(const floatx4*)&red[slot + (n * 2 + st) * 4];
                acc[n][st][0] += t[0]; acc[n][st][1] += t[1];
                acc[n][st][2] += t[2]; acc[n][st][3] += t[3];
            }
        psum[0] += red[slot + 32];
        psum[1] += red[slot + 33];

        #pragma unroll
        for (int st = 0; st < 2; ++st) {
            float L = psum[st];
            L += __shfl_xor(L, 16, 64);
            L += __shfl_xor(L, 32, 64);
            float Lr[4];
            #pragma unroll
            for (int r = 0; r < 4; ++r) Lr[r] = __shfl(L, lq * 4 + r, 64);
            #pragma unroll
            for (int n = 0; n < 4; ++n)
                #pragma unroll
                for (int r = 0; r < 4; ++r) {
                    int row = qb * 64 + qs + st * 16 + lq * 4 + r;
                    float v = acc[n][st][r] / Lr[r];
                    y[((long)(b * T_SEQ) + row) * CDIM + h * HDIM + n * 16 + lr] = f2h(v);
                }
        }
    }
}

extern "C" void kernel_launch(void* const* d_in, const int* in_sizes, int n_in,
                              void* d_out, int out_size, void* d_ws, size_t ws_size,
                              hipStream_t stream) {
    const float* x      = (const float*)d_in[0];
    const float* w_attn = (const float*)d_in[1];
    const float* b_attn = (const float*)d_in[2];
    const float* w_proj = (const float*)d_in[3];
    const float* b_proj = (const float*)d_in[4];
    float* out = (float*)d_out;

    char* ws = (char*)d_ws;
    _Float16* wTa = (_Float16*)(ws + 6291456);      // 3,538,944
    _Float16* wTp = (_Float16*)(ws + 9830400);      // 1,179,648
    _Float16* Qb  = (_Float16*)(ws + 11010048);     // 6,291,456
    _Float16* Kb  = (_Float16*)(ws + 17301504);     // 6,291,456
    _Float16* Vt  = (_Float16*)(ws + 23592960);     // 6,291,456
    _Float16* yb  = (_Float16*)(ws + 29884416);     // 6,291,456

    // MEASUREMENT: p x2, qkv x2, attn x3, proj x2 (all idempotent).
    // dur - 144.4 - 73.2 ~= attn_time + 1 launch gap (model-free).
    prologue<<<2304, 256, 0, stream>>>(w_attn, w_proj, wTa, wTp);
    prologue<<<2304, 256, 0, stream>>>(w_attn, w_proj, wTa, wTp);

    gemm_qkv<<<dim3(BT / 128, C3 / 96), 256, 0, stream>>>(x, wTa, b_attn, Qb, Kb, Vt);
    gemm_qkv<<<dim3(BT / 128, C3 / 96), 256, 0, stream>>>(x, wTa, b_attn, Qb, Kb, Vt);

    attn_kernel<<<BH * (T_SEQ / 64), 256, 0, stream>>>(Qb, Kb, Vt, yb);
    attn_kernel<<<BH * (T_SEQ / 64), 256, 0, stream>>>(Qb, Kb, Vt, yb);
    attn_kernel<<<BH * (T_SEQ / 64), 256, 0, stream>>>(Qb, Kb, Vt, yb);

    gemm_proj<<<dim3(BT / 64, CDIM / 96), 256, 0, stream>>>(yb, wTp, b_proj, out);
    gemm_proj<<<dim3(BT / 64, CDIM / 96), 256, 0, stream>>>(yb, wTp, b_proj, out);
}

// Round 8
// 138.359 us; speedup vs baseline: 1.7741x; 1.7741x over previous
//
#include <hip/hip_runtime.h>
#include <hip/hip_bf16.h>

// B=2, T=2048, C=768, H=12, D=64. 3C=2304. BT=4096.
// prologue (weight transposes); QKV GEMM 128x96 BK=64 reg-prefetch + fused
// x cast; causal flash attention: S^T form, 4 waves = 2 q-strips x 2
// key-halves, IN-REGISTER P via pi-permuted V columns (no Ps buffer, no
// P LDS round-trip); PV swapped (A=V^T, B=P^T in-reg) -> O^T accumulator,
// per-lane L, contiguous half4 y stores; proj GEMM 64x96.
// pi within each 32-key chunk: pos(k) = ((k&15)>>2)*8 + (k&3) + ((k>>4)&1)*4
// so lane quadrant lq supplies keys lq*4..+3 of subtiles 2kk,2kk+1 as its
// B-fragment j=0..7 -- exactly the values sacc already holds.
// (R8 = resubmit of R7: bench infra failed; kernel re-audited, unchanged.)

using half4   = __attribute__((ext_vector_type(4))) _Float16;
using half8   = __attribute__((ext_vector_type(8))) _Float16;
using floatx4 = __attribute__((ext_vector_type(4))) float;

#define T_SEQ 2048
#define NHEAD 12
#define HDIM 64
#define C3 2304
#define CDIM 768
#define BT 4096
#define BH 24

static __device__ inline _Float16 f2h(float f) { return (_Float16)f; }

// lgkm-only workgroup barrier: waits DS ops, leaves vmcnt in flight.
static __device__ inline void bar_lgkm() {
    __builtin_amdgcn_s_waitcnt(0xc07f);
    __builtin_amdgcn_s_barrier();
}

// ---------------- prologue: weight transposes only --------------------------
__global__ __launch_bounds__(256)
void prologue(const float* __restrict__ wa, const float* __restrict__ wp,
              _Float16* __restrict__ wTa, _Float16* __restrict__ wTp) {
    __shared__ float tile[32][33];
    int blk = blockIdx.x, tid = threadIdx.x;
    const float* w; _Float16* wT; int K, N, bx, by;
    if (blk < 1728) { w = wa; wT = wTa; K = CDIM; N = C3; bx = blk % 72; by = blk / 72; }
    else { int b2 = blk - 1728; w = wp; wT = wTp; K = CDIM; N = CDIM; bx = b2 % 24; by = b2 / 24; }
    int tx = tid & 31, ty = tid >> 5;
    #pragma unroll
    for (int j = 0; j < 32; j += 8) {
        int k = by * 32 + ty + j, n = bx * 32 + tx;
        tile[ty + j][tx] = w[(long)k * N + n];
    }
    __syncthreads();
    #pragma unroll
    for (int j = 0; j < 32; j += 8) {
        int nO = bx * 32 + ty + j, kO = by * 32 + tx;
        wT[(long)nO * K + kO] = f2h(tile[tx][ty + j]);
    }
}

// ---------------- QKV GEMM: 128x96 tile, BK=64, reg-prefetch, fused x cast ---
__global__ __launch_bounds__(256)
void gemm_qkv(const float* __restrict__ X, const _Float16* __restrict__ Bt,
              const float* __restrict__ bias,
              _Float16* __restrict__ Qb, _Float16* __restrict__ Kb,
              _Float16* __restrict__ Vt) {
    __shared__ __align__(16) _Float16 As[128 * 72];
    __shared__ __align__(16) _Float16 Bs[96 * 72];
    const int K = CDIM;
    int tid = threadIdx.x;
    int m0 = blockIdx.x * 128, n0 = blockIdx.y * 96;
    int w = tid >> 6, l = tid & 63;
    int wm = (w >> 1) * 64, wn = (w & 1) * 48;
    int lr = l & 15, lq = l >> 4;

    int rs = tid >> 3, cs = (tid & 7) * 8;

    floatx4 acc[4][3] = {};

    floatx4 Arf[4][2]; half8 Br[3];
    #pragma unroll
    for (int j = 0; j < 4; ++j) {
        Arf[j][0] = *(const floatx4*)&X[(long)(m0 + j * 32 + rs) * K + cs];
        Arf[j][1] = *(const floatx4*)&X[(long)(m0 + j * 32 + rs) * K + cs + 4];
    }
    #pragma unroll
    for (int j = 0; j < 3; ++j)
        Br[j] = *(const half8*)&Bt[(long)(n0 + j * 32 + rs) * K + cs];

    for (int kb = 0; kb < K; kb += 64) {
        #pragma unroll
        for (int j = 0; j < 4; ++j) {
            half8 h;
            #pragma unroll
            for (int e = 0; e < 4; ++e) { h[e] = f2h(Arf[j][0][e]); h[4 + e] = f2h(Arf[j][1][e]); }
            *(half8*)&As[(j * 32 + rs) * 72 + cs] = h;
        }
        #pragma unroll
        for (int j = 0; j < 3; ++j)
            *(half8*)&Bs[(j * 32 + rs) * 72 + cs] = Br[j];
        bar_lgkm();
        if (kb + 64 < K) {
            #pragma unroll
            for (int j = 0; j < 4; ++j) {
                Arf[j][0] = *(const floatx4*)&X[(long)(m0 + j * 32 + rs) * K + kb + 64 + cs];
                Arf[j][1] = *(const floatx4*)&X[(long)(m0 + j * 32 + rs) * K + kb + 64 + cs + 4];
            }
            #pragma unroll
            for (int j = 0; j < 3; ++j)
                Br[j] = *(const half8*)&Bt[(long)(n0 + j * 32 + rs) * K + kb + 64 + cs];
        }
        #pragma unroll
        for (int kh = 0; kh < 2; ++kh) {
            half8 af[4], bf[3];
            #pragma unroll
            for (int i = 0; i < 4; ++i)
                af[i] = *(const half8*)&As[(wm + i * 16 + lr) * 72 + kh * 32 + lq * 8];
            #pragma unroll
            for (int i = 0; i < 3; ++i)
                bf[i] = *(const half8*)&Bs[(wn + i * 16 + lr) * 72 + kh * 32 + lq * 8];
            #pragma unroll
            for (int mi = 0; mi < 4; ++mi)
                #pragma unroll
                for (int ni = 0; ni < 3; ++ni)
                    acc[mi][ni] = __builtin_amdgcn_mfma_f32_16x16x32_f16(af[mi], bf[ni], acc[mi][ni], 0, 0, 0);
        }
        bar_lgkm();
    }

    int region = n0 / CDIM;
    if (region < 2) {
        _Float16* O = region ? Kb : Qb;
        int nc0 = n0 - region * CDIM + wn;
        #pragma unroll
        for (int mi = 0; mi < 4; ++mi)
            #pragma unroll
            for (int ni = 0; ni < 3; ++ni) {
                int col = nc0 + ni * 16 + lr;
                float bsc = bias[region * CDIM + col];
                #pragma unroll
                for (int r = 0; r < 4; ++r) {
                    int row = m0 + wm + mi * 16 + lq * 4 + r;
                    O[(long)row * CDIM + col] = f2h(acc[mi][ni][r] + bsc);
                }
            }
    } else {
        #pragma unroll
        for (int mi = 0; mi < 4; ++mi)
            #pragma unroll
            for (int ni = 0; ni < 3; ++ni) {
                int cv = n0 - 2 * CDIM + wn + ni * 16 + lr;
                float bsc = bias[2 * CDIM + cv];
                int h = cv >> 6, d = cv & 63;
                int t0 = m0 + wm + mi * 16 + lq * 4;
                int bb = t0 >> 11, t = t0 & 2047;
                half4 hv;
                #pragma unroll
                for (int r = 0; r < 4; ++r) hv[r] = f2h(acc[mi][ni][r] + bsc);
                *(half4*)&Vt[(((long)bb * NHEAD + h) * HDIM + d) * T_SEQ + t] = hv;
            }
    }
}

// ---------------- proj GEMM: 64x96 tile, BK=64, reg-prefetch, fp32 out -------
__global__ __launch_bounds__(256)
void gemm_proj(const _Float16* __restrict__ A, const _Float16* __restrict__ Bt,
               const float* __restrict__ bias, float* __restrict__ Cout) {
    __shared__ __align__(16) _Float16 As[64 * 72];
    __shared__ __align__(16) _Float16 Bs[96 * 72];
    const int K = CDIM, N = CDIM;
    int tid = threadIdx.x;
    int m0 = blockIdx.x * 64, n0 = blockIdx.y * 96;
    int w = tid >> 6, l = tid & 63;
    int wm = (w >> 1) * 32, wn = (w & 1) * 48;
    int lr = l & 15, lq = l >> 4;

    int rs = tid >> 3, cs = (tid & 7) * 8;

    floatx4 acc[2][3] = {};

    half8 Ar[2], Br[3];
    #pragma unroll
    for (int j = 0; j < 2; ++j)
        Ar[j] = *(const half8*)&A[(long)(m0 + j * 32 + rs) * K + cs];
    #pragma unroll
    for (int j = 0; j < 3; ++j)
        Br[j] = *(const half8*)&Bt[(long)(n0 + j * 32 + rs) * K + cs];

    for (int kb = 0; kb < K; kb += 64) {
        #pragma unroll
        for (int j = 0; j < 2; ++j)
            *(half8*)&As[(j * 32 + rs) * 72 + cs] = Ar[j];
        #pragma unroll
        for (int j = 0; j < 3; ++j)
            *(half8*)&Bs[(j * 32 + rs) * 72 + cs] = Br[j];
        bar_lgkm();
        if (kb + 64 < K) {
            #pragma unroll
            for (int j = 0; j < 2; ++j)
                Ar[j] = *(const half8*)&A[(long)(m0 + j * 32 + rs) * K + kb + 64 + cs];
            #pragma unroll
            for (int j = 0; j < 3; ++j)
                Br[j] = *(const half8*)&Bt[(long)(n0 + j * 32 + rs) * K + kb + 64 + cs];
        }
        #pragma unroll
        for (int kh = 0; kh < 2; ++kh) {
            half8 af[2], bf[3];
            #pragma unroll
            for (int i = 0; i < 2; ++i)
                af[i] = *(const half8*)&As[(wm + i * 16 + lr) * 72 + kh * 32 + lq * 8];
            #pragma unroll
            for (int i = 0; i < 3; ++i)
                bf[i] = *(const half8*)&Bs[(wn + i * 16 + lr) * 72 + kh * 32 + lq * 8];
            #pragma unroll
            for (int mi = 0; mi < 2; ++mi)
                #pragma unroll
                for (int ni = 0; ni < 3; ++ni)
                    acc[mi][ni] = __builtin_amdgcn_mfma_f32_16x16x32_f16(af[mi], bf[ni], acc[mi][ni], 0, 0, 0);
        }
        bar_lgkm();
    }
    #pragma unroll
    for (int mi = 0; mi < 2; ++mi)
        #pragma unroll
        for (int ni = 0; ni < 3; ++ni) {
            int col = n0 + wn + ni * 16 + lr;
            float b = bias[col];
            #pragma unroll
            for (int r = 0; r < 4; ++r) {
                int row = m0 + wm + mi * 16 + lq * 4 + r;
                Cout[(long)row * N + col] = acc[mi][ni][r] + b;
            }
        }
}

// ---------------- causal flash attention: in-register P ----------------------
__global__ __launch_bounds__(256)
void attn_kernel(const _Float16* __restrict__ Qb, const _Float16* __restrict__ Kb,
                 const _Float16* __restrict__ Vt, _Float16* __restrict__ y) {
    __shared__ __align__(16) _Float16 Ks[128 * 72];     // [key][d]        18432 B
    __shared__ __align__(16) _Float16 Vs[64 * 136];     // [d][pi(key)]    17408 B
    int tid = threadIdx.x;
    int w = tid >> 6, l = tid & 63;
    int lr = l & 15, lq = l >> 4;
    int qs = (w & 1) * 32;          // q-strip base within 64-q block
    int kh2 = (w >> 1) * 64;        // key-half base within 128-key tile
    int i = blockIdx.x;
    int round = i >> 8, c = i & 255;
    int r_ = (round == 0) ? c : (round == 1 ? 767 - c : 256 + c);
    int qb = 31 - r_ / 24;
    int bh = r_ % 24;
    int b = bh / NHEAD, h = bh % NHEAD;

    const _Float16* Qp = Qb + (long)b * T_SEQ * CDIM + h * HDIM;
    const _Float16* Kg = Kb + (long)b * T_SEQ * CDIM + h * HDIM;
    const _Float16* Vg = Vt + (long)bh * HDIM * T_SEQ;

    int kr = tid >> 3, kc = (tid & 7) * 8;     // K staging: rows j*32 + kr
    int vr = tid >> 4, vc = (tid & 15) * 8;    // V staging: rows j*16 + vr
    // pi column base: lo half4 -> vpc, hi half4 -> vpc+8 (within 32-chunk)
    int vpc = (vc & ~31) + ((vc >> 3) & 1) * 16 + ((vc >> 4) & 1) * 4;

    const float qscale = 0.125f * 1.44269504f;
    half8 aq[2][2];
    #pragma unroll
    for (int st = 0; st < 2; ++st)
        #pragma unroll
        for (int kk = 0; kk < 2; ++kk) {
            aq[st][kk] = *(const half8*)&Qp[(long)(qb * 64 + qs + st * 16 + lr) * CDIM + kk * 32 + lq * 8];
            #pragma unroll
            for (int j = 0; j < 8; ++j) aq[st][kk][j] = f2h((float)aq[st][kk][j] * qscale);
        }

    int nk = (qb + 2) >> 1;

    half8 Kr[4], Vr[4];
    #pragma unroll
    for (int j = 0; j < 4; ++j) {
        Kr[j] = *(const half8*)&Kg[(long)(j * 32 + kr) * CDIM + kc];
        Vr[j] = *(const half8*)&Vg[(long)(j * 16 + vr) * T_SEQ + vc];
    }

    float psum[2] = {0.f, 0.f};
    floatx4 acc[4][2] = {};        // [n][strip]: O^T[d=n*16+lq*4+r][q=qs+st*16+lr]
    int qrow0 = qb * 64 + qs + lr, qrow1 = qb * 64 + qs + 16 + lr;

    for (int kt = 0; kt < nk; ++kt) {
        int kbase = kt * 128;
        #pragma unroll
        for (int j = 0; j < 4; ++j) {
            *(half8*)&Ks[(j * 32 + kr) * 72 + kc] = Kr[j];
            half4 lo, hi;
            #pragma unroll
            for (int e = 0; e < 4; ++e) { lo[e] = Vr[j][e]; hi[e] = Vr[j][4 + e]; }
            *(half4*)&Vs[(j * 16 + vr) * 136 + vpc] = lo;
            *(half4*)&Vs[(j * 16 + vr) * 136 + vpc + 8] = hi;
        }
        bar_lgkm();                  // K/V writes visible; vmcnt free-running
        if (kt + 1 < nk) {
            int nb = kbase + 128;
            #pragma unroll
            for (int j = 0; j < 4; ++j) {
                Kr[j] = *(const half8*)&Kg[(long)(nb + j * 32 + kr) * CDIM + kc];
                Vr[j] = *(const half8*)&Vg[(long)(j * 16 + vr) * T_SEQ + nb + vc];
            }
        }

        // S^T = K Q^T over this wave's 64-key half x 32-q strip.
        floatx4 sacc[4][2];
        #pragma unroll
        for (int s = 0; s < 4; ++s)
            #pragma unroll
            for (int st = 0; st < 2; ++st) sacc[s][st] = floatx4{0.f, 0.f, 0.f, 0.f};
        #pragma unroll
        for (int s = 0; s < 4; ++s) {
            #pragma unroll
            for (int kk = 0; kk < 2; ++kk) {
                half8 bk = *(const half8*)&Ks[(kh2 + s * 16 + lr) * 72 + kk * 32 + lq * 8];
                sacc[s][0] = __builtin_amdgcn_mfma_f32_16x16x32_f16(bk, aq[0][kk], sacc[s][0], 0, 0, 0);
                sacc[s][1] = __builtin_amdgcn_mfma_f32_16x16x32_f16(bk, aq[1][kk], sacc[s][1], 0, 0, 0);
            }
        }

        // softmax (fixed-max) + pack P into registers: ph[st][s] = this lane's
        // 4 keys (lq*4..+3) of subtile s, query q = qs+st*16+lr.
        half4 ph[2][4];
        if (kt == nk - 1) {   // tile containing the diagonal
            #pragma unroll
            for (int s = 0; s < 4; ++s)
                #pragma unroll
                for (int r = 0; r < 4; ++r) {
                    int key = kbase + kh2 + s * 16 + lq * 4 + r;
                    float p0 = (key > qrow0) ? 0.f : __builtin_amdgcn_exp2f(sacc[s][0][r]);
                    float p1 = (key > qrow1) ? 0.f : __builtin_amdgcn_exp2f(sacc[s][1][r]);
                    psum[0] += p0; psum[1] += p1;
                    ph[0][s][r] = f2h(p0); ph[1][s][r] = f2h(p1);
                }
        } else {
            #pragma unroll
            for (int s = 0; s < 4; ++s)
                #pragma unroll
                for (int r = 0; r < 4; ++r) {
                    float p0 = __builtin_amdgcn_exp2f(sacc[s][0][r]);
                    float p1 = __builtin_amdgcn_exp2f(sacc[s][1][r]);
                    psum[0] += p0; psum[1] += p1;
                    ph[0][s][r] = f2h(p0); ph[1][s][r] = f2h(p1);
                }
        }

        // PV swapped: O^T = V^T . P^T. A = V^T (Vs, pi-ordered cols), B = P^T
        // (in-reg: j=0..3 from subtile 2kk, j=4..7 from subtile 2kk+1).
        #pragma unroll
        for (int kk = 0; kk < 2; ++kk) {
            half8 bp0, bp1;
            #pragma unroll
            for (int e = 0; e < 4; ++e) {
                bp0[e] = ph[0][2 * kk][e];     bp0[4 + e] = ph[0][2 * kk + 1][e];
                bp1[e] = ph[1][2 * kk][e];     bp1[4 + e] = ph[1][2 * kk + 1][e];
            }
            #pragma unroll
            for (int n = 0; n < 4; ++n) {
                half8 av = *(const half8*)&Vs[(n * 16 + lr) * 136 + kh2 + kk * 32 + lq * 8];
                acc[n][0] = __builtin_amdgcn_mfma_f32_16x16x32_f16(av, bp0, acc[n][0], 0, 0, 0);
                acc[n][1] = __builtin_amdgcn_mfma_f32_16x16x32_f16(av, bp1, acc[n][1], 0, 0, 0);
            }
        }
        bar_lgkm();                  // reads retired before next K/V overwrite
    }

    // cross-pair reduction: waves 2,3 hand partials to waves 0,1 via Ks.
    float* red = (float*)Ks;                   // 18432 B = 128*36*4
    int slot = ((w & 1) * 64 + l) * 36;
    if (w >= 2) {
        #pragma unroll
        for (int n = 0; n < 4; ++n)
            #pragma unroll
            for (int st = 0; st < 2; ++st)
                *(floatx4*)&red[slot + (n * 2 + st) * 4] = acc[n][st];
        red[slot + 32] = psum[0];
        red[slot + 33] = psum[1];
    }
    __syncthreads();
    if (w < 2) {
        #pragma unroll
        for (int n = 0; n < 4; ++n)
            #pragma unroll
            for (int st = 0; st < 2; ++st) {
                floatx4 t = *(const floatx4*)&red[slot + (n * 2 + st) * 4];
                acc[n][st][0] += t[0]; acc[n][st][1] += t[1];
                acc[n][st][2] += t[2]; acc[n][st][3] += t[3];
            }
        psum[0] += red[slot + 32];
        psum[1] += red[slot + 33];

        #pragma unroll
        for (int st = 0; st < 2; ++st) {
            float L = psum[st];
            L += __shfl_xor(L, 16, 64);
            L += __shfl_xor(L, 32, 64);
            float inv = 1.f / L;               // this lane's q = qs+st*16+lr
            #pragma unroll
            for (int n = 0; n < 4; ++n) {
                half4 hv;
                #pragma unroll
                for (int r = 0; r < 4; ++r) hv[r] = f2h(acc[n][st][r] * inv);
                int row = qb * 64 + qs + st * 16 + lr;
                *(half4*)&y[((long)(b * T_SEQ) + row) * CDIM + h * HDIM + n * 16 + lq * 4] = hv;
            }
        }
    }
}

extern "C" void kernel_launch(void* const* d_in, const int* in_sizes, int n_in,
                              void* d_out, int out_size, void* d_ws, size_t ws_size,
                              hipStream_t stream) {
    const float* x      = (const float*)d_in[0];
    const float* w_attn = (const float*)d_in[1];
    const float* b_attn = (const float*)d_in[2];
    const float* w_proj = (const float*)d_in[3];
    const float* b_proj = (const float*)d_in[4];
    float* out = (float*)d_out;

    char* ws = (char*)d_ws;
    _Float16* wTa = (_Float16*)(ws + 6291456);      // 3,538,944
    _Float16* wTp = (_Float16*)(ws + 9830400);      // 1,179,648
    _Float16* Qb  = (_Float16*)(ws + 11010048);     // 6,291,456
    _Float16* Kb  = (_Float16*)(ws + 17301504);     // 6,291,456
    _Float16* Vt  = (_Float16*)(ws + 23592960);     // 6,291,456
    _Float16* yb  = (_Float16*)(ws + 29884416);     // 6,291,456

    prologue<<<2304, 256, 0, stream>>>(w_attn, w_proj, wTa, wTp);

    gemm_qkv<<<dim3(BT / 128, C3 / 96), 256, 0, stream>>>(x, wTa, b_attn, Qb, Kb, Vt);

    attn_kernel<<<BH * (T_SEQ / 64), 256, 0, stream>>>(Qb, Kb, Vt, yb);

    gemm_proj<<<dim3(BT / 64, CDIM / 96), 256, 0, stream>>>(yb, wTp, b_proj, out);
}